// Round 13
// baseline (3513.730 us; speedup 1.0000x reference)
//
#include <hip/hip_runtime.h>
#include <stdint.h>

// Persistent-LSTM, round 13 (= r12 with the nontemporal-store type fixed).
//  - 256 WGs x 128 threads (2 waves). g = bid&3 (batch rows 16g..16g+15,
//    XCD-pair locality), m = bid>>2 (u-cols 8m..8m+7).
//  - hbuf: plain bf16 [2][64][512] parity double buffer; spread tags
//    [4][64][16] (one per 64-B line); wave-0-only tag poll + barrier hand-off.
//  - RELEASE RESTRUCTURE:
//    (1) h published as 16 coalesced 16-B stores (one per row) instead of
//        128 scattered 2-B stores: gate threads stage hh (f32) in LDS; each
//        wave re-reads its OWN 8 rows (intra-wave, explicit lgkmcnt), packs
//        with v_cvt_pk_bf16_f32, stores dwordx4 sc1. The release vmcnt(0)
//        now waits one coalesced ack, not 128 serialized micro-acks.
//    (2) out[] moves to wave 1 entirely, AFTER the release sync (tanh also
//        computed there): wave 0 -- the poller -- never carries an HBM
//        out-store ack in its vmcnt queue; wave 1's acks drain during
//        wave 0's next-step poll (hidden).
//  - Release ordering proof unchanged: each wave drains its own h stores
//    (vmcnt(0)) before __syncthreads; tag stored by tid0 after the sync =>
//    tag visible => all 16 rows at IF$. 2-buffer WAR safety as r10/r11.

#define Tt   1024
#define Uu   512
#define G4U  2048
#define NWG  256
#define NTHR 128
#define TAGSTRIDE 16                               // u32s per tag line (64 B)

#define WF_ELEMS (2 * 24 * 64 * 8)                 // 24576 bf16 = 48 KB
#define WF_BYTES (WF_ELEMS * 2)
#define ZB_PLANE (16 * 17)                         // padded 16x16 f32 tile
#define ZB_BYTES (4 * ZB_PLANE * 4)                // 4352 B
#define STG_BYTES (16 * 8 * 4)                     // hh staging: 512 B
#define SMEM_BYTES (WF_BYTES + ZB_BYTES + STG_BYTES)

typedef short  bf16x8 __attribute__((ext_vector_type(8)));
typedef float  f32x4  __attribute__((ext_vector_type(4)));
typedef int    int4v  __attribute__((ext_vector_type(4)));
typedef unsigned int u32;

__device__ __forceinline__ unsigned short f2bf(float f) {
  u32 u = __builtin_bit_cast(u32, f);
  u += 0x7fffu + ((u >> 16) & 1u);                 // RNE (finite inputs)
  return (unsigned short)(u >> 16);
}

// Agent scope (sc1): bypass L1 + non-coherent per-XCD L2; serve at IF$.
__device__ __forceinline__ int4v load16_ag(const unsigned short* p) {
  int4v r;
  asm volatile("global_load_dwordx4 %0, %1, off sc1"
               : "=v"(r) : "v"(p) : "memory");
  return r;
}
__device__ __forceinline__ void store16_ag(unsigned short* p, int4v v) {
  asm volatile("global_store_dwordx4 %0, %1, off sc1"
               :: "v"(p), "v"(v) : "memory");
}
__device__ __forceinline__ void store4_ag(u32* p, u32 v) {
  asm volatile("global_store_dword %0, %1, off sc1"
               :: "v"(p), "v"(v) : "memory");
}
__device__ __forceinline__ u32 load_tag_wait(const u32* p) {
  u32 r;
  asm volatile("global_load_dword %0, %1, off sc1\n\ts_waitcnt vmcnt(0)"
               : "=v"(r) : "v"(p) : "memory");
  return r;
}

__device__ __forceinline__ float sigf(float z) {
  return __builtin_amdgcn_rcpf(1.f + __expf(-z));
}
__device__ __forceinline__ float tanh_fast(float v) {
  const float e = __expf(-2.f * fabsf(v));
  const float r = (1.f - e) * __builtin_amdgcn_rcpf(1.f + e);
  return copysignf(r, v);
}

extern "C" __global__ void __launch_bounds__(NTHR, 1)
lstm_persistent(const float* __restrict__ x,
                const float* __restrict__ Wk,
                const float* __restrict__ Rk,
                const float* __restrict__ bias,
                float* __restrict__ out,
                unsigned short* __restrict__ hbuf,  // [2][64][512] bf16
                u32* __restrict__ tags)             // [4][64][16] spread
{
  extern __shared__ char smem[];
  unsigned short* wf     = (unsigned short*)smem;          // [nt][kt][lane][8]
  float*          zbuf   = (float*)(smem + WF_BYTES);      // [w][nt][16][17]
  float*          ostage = (float*)(smem + WF_BYTES + ZB_BYTES); // [16][8]

  const int bid = blockIdx.x;
  const int tid = threadIdx.x;
  const int w   = tid >> 6;
  const int l   = tid & 63;
  const int g   = bid & 3;         // row group on XCD pair {g, g+4}
  const int m   = bid >> 2;        // u-cols 8m..8m+7

  // ---- one-time weight staging into MFMA B-fragment order ----
  for (int i = tid; i < WF_ELEMS; i += NTHR) {
    const int j    = i & 7;
    const int lane = (i >> 3) & 63;
    const int kt   = (i >> 9) % 24;
    const int nt   = (i >> 9) / 24;
    const int k    = kt * 32 + ((lane >> 4) << 3) + j;     // 0..767
    const int n    = nt * 16 + (lane & 15);                // 0..31
    const int zc   = (n >> 3) * Uu + m * 8 + (n & 7);      // gate*512 + u
    const float v  = (k < 256) ? Wk[(size_t)k * G4U + zc]
                               : Rk[(size_t)(k - 256) * G4U + zc];
    wf[i] = f2bf(v);
  }
  __syncthreads();

  // ---- preload x-part weight fragments (kt = 2q+w, q=0..3) ----
  bf16x8 wfx[4][2];
  #pragma unroll
  for (int q = 0; q < 4; ++q)
    #pragma unroll
    for (int nt = 0; nt < 2; ++nt)
      wfx[q][nt] = *(const bf16x8*)(wf + (((nt * 24) + (2 * q + w)) * 64 + l) * 8);

  // ---- combine-role constants (one (row,u) pair per thread) ----
  const int row_c = tid >> 3;                  // 0..15
  const int uu    = tid & 7;
  float breg[4];
  #pragma unroll
  for (int gg = 0; gg < 4; ++gg) breg[gg] = bias[gg * Uu + m * 8 + uu];
  float creg = 0.f;

  // ---- load-role constants (lane-level, MFMA A-fragment) ----
  const int b_ld = g * 16 + (l & 15);
  const int kq   = (l >> 4) * 8;
  // wave 0: lane l polls producer (g, l)'s dedicated 64-B tag line
  const u32* tagp = tags + ((size_t)g * 64 + l) * TAGSTRIDE;
  // release: wave w, lane l<8 stores row (w*8 + l)
  unsigned short* hq0 =
      hbuf + ((size_t)(g * 16 + w * 8 + (l & 7))) * Uu + m * 8;

  for (int t = 0; t < Tt; ++t) {
    // ---- wave 0 issues the first tag probe early (overlaps x phase) ----
    u32 tv = (u32)t;                             // wave 1: vacuous pass
    if (w == 0)
      asm volatile("global_load_dword %0, %1, off sc1"
                   : "=v"(tv) : "v"(tagp) : "memory");

    // ---- x phase: fp32 loads + cvt + 8 MFMAs (kt = 2q+w) ----
    f32x4 aX0 = {0.f, 0.f, 0.f, 0.f};
    f32x4 aX1 = {0.f, 0.f, 0.f, 0.f};
    const float* xp = x + ((size_t)b_ld * Tt + t) * 256 + kq;
    #pragma unroll
    for (int q = 0; q < 4; ++q) {
      const int kt = 2 * q + w;
      const f32x4 v0 = *(const f32x4*)(xp + kt * 32);
      const f32x4 v1 = *(const f32x4*)(xp + kt * 32 + 4);
      int r0, r1, r2, r3;
      asm("v_cvt_pk_bf16_f32 %0, %1, %2" : "=v"(r0) : "v"(v0[0]), "v"(v0[1]));
      asm("v_cvt_pk_bf16_f32 %0, %1, %2" : "=v"(r1) : "v"(v0[2]), "v"(v0[3]));
      asm("v_cvt_pk_bf16_f32 %0, %1, %2" : "=v"(r2) : "v"(v1[0]), "v"(v1[1]));
      asm("v_cvt_pk_bf16_f32 %0, %1, %2" : "=v"(r3) : "v"(v1[2]), "v"(v1[3]));
      const int4v ai = {r0, r1, r2, r3};
      const bf16x8 a = __builtin_bit_cast(bf16x8, ai);
      aX0 = __builtin_amdgcn_mfma_f32_16x16x32_bf16(a, wfx[q][0], aX0, 0, 0, 0);
      aX1 = __builtin_amdgcn_mfma_f32_16x16x32_bf16(a, wfx[q][1], aX1, 0, 0, 0);
    }

    // ---- acquire: wave 0 polls spread tags; wave 1 waits at barrier ----
    asm volatile("s_waitcnt vmcnt(0)" ::: "memory");
    __builtin_amdgcn_sched_barrier(0);
    if (w == 0) {
      while (!__all(tv >= (u32)t)) {
        __builtin_amdgcn_s_sleep(1);
        tv = load_tag_wait(tagp);
        __builtin_amdgcn_sched_barrier(0);
      }
    }
    __builtin_amdgcn_s_barrier();                // hand-off: tags observed
    __builtin_amdgcn_sched_barrier(0);

    // ---- h data loads: issued strictly after the tag pass ----
    const unsigned short* hrow =
        hbuf + ((size_t)(t & 1) * 64 + b_ld) * Uu + kq;
    int4v hf[8];
    #pragma unroll
    for (int q = 0; q < 8; ++q)
      hf[q] = load16_ag(hrow + (2 * q + w) * 32);
    asm volatile("s_waitcnt vmcnt(0)" ::: "memory");
    __builtin_amdgcn_sched_barrier(0);

    // ---- h phase: 16 MFMAs, contiguous fragments ----
    f32x4 aH0 = {0.f, 0.f, 0.f, 0.f};
    f32x4 aH1 = {0.f, 0.f, 0.f, 0.f};
    #pragma unroll
    for (int q = 0; q < 8; ++q) {
      const int kt = 8 + 2 * q + w;
      const bf16x8 a = __builtin_bit_cast(bf16x8, hf[q]);
      const bf16x8 b0 = *(const bf16x8*)(wf + ((0 * 24 + kt) * 64 + l) * 8);
      const bf16x8 b1 = *(const bf16x8*)(wf + ((1 * 24 + kt) * 64 + l) * 8);
      aH0 = __builtin_amdgcn_mfma_f32_16x16x32_bf16(a, b0, aH0, 0, 0, 0);
      aH1 = __builtin_amdgcn_mfma_f32_16x16x32_bf16(a, b1, aH1, 0, 0, 0);
    }

    const f32x4 z0 = aX0 + aH0;
    const f32x4 z1 = aX1 + aH1;

    // ---- cross-wave z reduce through zbuf ----
    __syncthreads();                             // WAR vs previous combine
    {
      float* zb = zbuf + ((w * 2 + 0) * 16 + (l >> 4) * 4) * 17 + (l & 15);
      #pragma unroll
      for (int r = 0; r < 4; ++r) {
        zb[r * 17]           = z0[r];
        zb[r * 17 + 16 * 17] = z1[r];            // nt=1 plane
      }
    }
    __syncthreads();

    // ---- gate math (fp32), cell update; stage hh to LDS ----
    float z[4];
    #pragma unroll
    for (int gg = 0; gg < 4; ++gg) {
      const int n  = gg * 8 + uu;
      const int nt = n >> 4, nc = n & 15;
      z[gg] = zbuf[((0 + nt) * 16 + row_c) * 17 + nc]
            + zbuf[((2 + nt) * 16 + row_c) * 17 + nc]
            + breg[gg];
    }
    const float ig = sigf(z[0]);
    const float fg = sigf(z[1]);
    const float og = sigf(z[3]);
    const float cc = fg * creg + ig * z[2];
    creg = cc;
    ostage[tid] = og * cc;                       // [row 0..15][u 0..7], f32

    // ---- release: coalesced h stores (own 8 rows per wave, intra-wave) ----
    asm volatile("s_waitcnt lgkmcnt(0)" ::: "memory");  // ds_write visible
    __builtin_amdgcn_sched_barrier(0);
    if (l < 8) {
      const float* sr = ostage + (w * 8 + l) * 8;       // own-wave rows only
      const f32x4 a0 = *(const f32x4*)(sr);
      const f32x4 a1 = *(const f32x4*)(sr + 4);
      int p0, p1, p2, p3;
      asm("v_cvt_pk_bf16_f32 %0, %1, %2" : "=v"(p0) : "v"(a0[0]), "v"(a0[1]));
      asm("v_cvt_pk_bf16_f32 %0, %1, %2" : "=v"(p1) : "v"(a0[2]), "v"(a0[3]));
      asm("v_cvt_pk_bf16_f32 %0, %1, %2" : "=v"(p2) : "v"(a1[0]), "v"(a1[1]));
      asm("v_cvt_pk_bf16_f32 %0, %1, %2" : "=v"(p3) : "v"(a1[2]), "v"(a1[3]));
      const int4v hv = {p0, p1, p2, p3};
      store16_ag(hq0 + (size_t)(((t + 1) & 1) * 64) * Uu, hv);
    }
    asm volatile("s_waitcnt vmcnt(0)" ::: "memory");    // one coalesced ack
    __builtin_amdgcn_sched_barrier(0);
    __syncthreads();                              // both waves' h at IF$
    if (tid == 0)
      store4_ag(tags + ((size_t)g * 64 + m) * TAGSTRIDE, (u32)(t + 1));

    // ---- out: wave 1 only, AFTER release (never in wave 0's vmcnt) ----
    if (w == 1 && l < 16) {
      const float* sr = ostage + l * 8;
      float* op = out + ((size_t)(g * 16 + l) * Tt + t) * Uu + m * 8;
      f32x4 o0 = *(const f32x4*)(sr);
      f32x4 o1 = *(const f32x4*)(sr + 4);
      o0[0] = tanh_fast(o0[0]); o0[1] = tanh_fast(o0[1]);
      o0[2] = tanh_fast(o0[2]); o0[3] = tanh_fast(o0[3]);
      o1[0] = tanh_fast(o1[0]); o1[1] = tanh_fast(o1[1]);
      o1[2] = tanh_fast(o1[2]); o1[3] = tanh_fast(o1[3]);
      __builtin_nontemporal_store(o0, (f32x4*)op);
      __builtin_nontemporal_store(o1, (f32x4*)(op + 4));
    }
  }
}

extern "C" void kernel_launch(void* const* d_in, const int* in_sizes, int n_in,
                              void* d_out, int out_size, void* d_ws, size_t ws_size,
                              hipStream_t stream) {
  const float* x    = (const float*)d_in[0];
  const float* Wk   = (const float*)d_in[1];
  const float* Rk   = (const float*)d_in[2];
  const float* bias = (const float*)d_in[3];
  float* out = (float*)d_out;
  unsigned short* hbuf = (unsigned short*)d_ws;
  u32* tags = (u32*)((char*)d_ws + (size_t)2 * 64 * Uu * sizeof(unsigned short));

  // zeroed hbuf = h_0 = 0 (both parities); tags 0 = "h_0 published".
  (void)hipMemsetAsync(d_ws, 0,
                       (size_t)2 * 64 * Uu * sizeof(unsigned short)
                         + (size_t)4 * 64 * TAGSTRIDE * sizeof(u32),
                       stream);

  (void)hipFuncSetAttribute((const void*)lstm_persistent,
                            hipFuncAttributeMaxDynamicSharedMemorySize,
                            SMEM_BYTES);

  hipLaunchKernelGGL(lstm_persistent, dim3(NWG), dim3(NTHR), SMEM_BYTES, stream,
                     x, Wk, Rk, bias, out, hbuf, tags);
}